// Round 3
// baseline (419.960 us; speedup 1.0000x reference)
//
#include <hip/hip_runtime.h>

typedef unsigned short u16;
typedef float  f32x4  __attribute__((ext_vector_type(4)));
typedef __bf16 bf16x8 __attribute__((ext_vector_type(8)));
typedef u16    u16x2  __attribute__((ext_vector_type(2)));
typedef u16    u16x4  __attribute__((ext_vector_type(4)));

#define D_MODEL 1024
#define D_INNER 2048
#define B_SZ    2
#define SEQ     4096
#define MROWS   (B_SZ * SEQ)       // 8192
#define LTAPS   64                 // f[tau] ~ 0.4^tau -> negligible at 64
#define VROW    136                // VT row stride (u16): 272 B, 16B-aligned

__device__ __forceinline__ u16 f2bf(float f) {
    return __builtin_bit_cast(u16, (__bf16)f);   // HW v_cvt (RTNE) on gfx950
}
__device__ __forceinline__ float bf2f(u16 h) {
    unsigned u = ((unsigned)h) << 16;
    return __builtin_bit_cast(float, u);
}

typedef __attribute__((address_space(1))) void gv_t;
typedef __attribute__((address_space(3))) void lv_t;
__device__ __forceinline__ void glds16(const u16* g, u16* l) {
    __builtin_amdgcn_global_load_lds((gv_t*)g, (lv_t*)l, 16, 0, 0);
}
// gfx9 waitcnt imm: vm[3:0]+[15:14], exp[6:4], lgkm[11:8]
#define WAIT_VM4   0x0F74          // vmcnt(4), others max
#define WAIT_VM0   0x0F70          // vmcnt(0), others max
#define WAIT_LGKM0 0xC07F          // lgkmcnt(0), others max

// ---------------------------------------------------------------------------
// Prep (one launch): blocks [0,8192) cvt x->bf16; [8192,10240) transpose Win;
// [10240,12288) transpose Wout; block 12288 builds Amat64[64][128] bf16;
// blocks [12289,20481) fill out with bias (GEMM2 accumulates atomically).
// ---------------------------------------------------------------------------
__device__ __forceinline__ void transpose_tile(
    const float* __restrict__ in, u16* __restrict__ out,
    int R, int C, int c0, int r0, int tid, float (*tile)[33])
{
    const int tx = tid & 31, ty = tid >> 5;   // 32 x 8
    for (int k = 0; k < 32; k += 8)
        tile[ty + k][tx] = in[(size_t)(r0 + ty + k) * C + c0 + tx];
    __syncthreads();
    for (int k = 0; k < 32; k += 8)
        out[(size_t)(c0 + ty + k) * R + r0 + tx] = f2bf(tile[tx][ty + k]);
}

__global__ __launch_bounds__(256) void prep_kernel(
    const float* __restrict__ x, u16* __restrict__ xb,
    const float* __restrict__ Win, u16* __restrict__ WinT,
    const float* __restrict__ Wout, u16* __restrict__ WoutT,
    const float* __restrict__ A, const float* __restrict__ Bp,
    const float* __restrict__ Cp, const float* __restrict__ Dp,
    u16* __restrict__ Amat64,
    const float* __restrict__ bout, float* __restrict__ outp)
{
    __shared__ float tile[32][33];
    __shared__ float fs[LTAPS];
    const int bx = blockIdx.x, tid = threadIdx.x;
    if (bx < 8192) {
        size_t i = ((size_t)bx * 256 + tid) * 4;
        f32x4 v = *(const f32x4*)(x + i);
        u16x4 o;
        o.x = f2bf(v.x); o.y = f2bf(v.y); o.z = f2bf(v.z); o.w = f2bf(v.w);
        *(u16x4*)(xb + i) = o;
    } else if (bx < 10240) {
        const int flat = bx - 8192;                      // Win: 1024 x 2048
        transpose_tile(Win, WinT, 1024, 2048,
                       (flat & 63) * 32, (flat >> 6) * 32, tid, tile);
    } else if (bx < 12288) {
        const int flat = bx - 10240;                     // Wout: 2048 x 1024
        transpose_tile(Wout, WoutT, 2048, 1024,
                       (flat & 31) * 32, (flat >> 5) * 32, tid, tile);
    } else if (bx == 12288) {
        if (tid < 64) {
            const int i = tid & 15;          // lanes replicate in groups of 16
            float Atr[16];
            for (int j = 0; j < 16; j++) Atr[j] = tanhf(A[i * 16 + j]);
            float p = Bp[i];
            const float c  = Cp[i];
            const float d0 = Dp[0];
            for (int t = 0; t < LTAPS; t++) {
                float fv = c * p;
                fv += __shfl_xor(fv, 1); fv += __shfl_xor(fv, 2);
                fv += __shfl_xor(fv, 4); fv += __shfl_xor(fv, 8);
                if (tid == 0) fs[t] = fv + (t == 0 ? d0 : 0.f);
                float n0 = 0.f, n1 = 0.f, n2 = 0.f, n3 = 0.f;
                #pragma unroll
                for (int j = 0; j < 4; j++) {
                    n0 = fmaf(Atr[j],      __shfl(p, j),      n0);
                    n1 = fmaf(Atr[j + 4],  __shfl(p, j + 4),  n1);
                    n2 = fmaf(Atr[j + 8],  __shfl(p, j + 8),  n2);
                    n3 = fmaf(Atr[j + 12], __shfl(p, j + 12), n3);
                }
                p = (n0 + n1) + (n2 + n3);
            }
        }
        __syncthreads();
        for (int idx = tid; idx < 64 * 128; idx += 256) {
            const int i = idx >> 7, j = idx & 127;
            const int tau = 64 + i - j;
            float v = (tau >= 0 && tau < LTAPS) ? fs[tau] : 0.f;
            Amat64[idx] = f2bf(v);
        }
    } else {                                             // bias fill of out
        const size_t e = ((size_t)(bx - 12289) * 256 + tid) * 4;
        const int col = (int)(e & 1023);
        *(f32x4*)(outp + e) = *(const f32x4*)(bout + col);
    }
}

// ---------------------------------------------------------------------------
// 4-buffer-ring bt-GEMM, 256x256 tile, BK=32, 512 thr = 8 waves (2m x 4n),
// wave tile 128x64 (FM=8 via M-half split, FN=4).
// C[m][n] = sum_k A[m][k]*BT[n][k] (+ bias[n] in MODE 0).
// LDS: 4 ring buffers x 32 KB (A 16 KB + B 16 KB) = 128 KB. Staging runs TWO
// K-tiles ahead: during tile t, phase 0 stages A(t+2), phase 1 stages B(t+2)
// into buffer (t+2)&3 -- last read at tile t-2, provably dead (barriers).
// Phase (m201 order; reads BEFORE barrier so the barrier absorbs ds latency;
// vmcnt counted once per tile, never 0 in the main loop):
//   ds_read frags (8 at p0 incl. B, 4 at p1; B frags reused across halves)
//   2 x glds16 stage   [p1 only: vmcnt(4)]
//   s_barrier; lgkmcnt(0); setprio(1); 16 MFMA; setprio(0); s_barrier
// Swizzle (identical to verified r1): within-region byte offset
// q ^= ((q>>7)&7)<<4 applied to the GLOBAL source addr (LDS dest linear for
// global_load_lds) and to ds_read addrs -> 0 bank conflicts (verified).
// MODE 0: bf16 store + bias. MODE 2: split-K=2, fp32 atomic accumulate into
// bias-prefilled out. Grid 256 both: GEMM1 32mt x 8nt; GEMM2 32mt x 4nt x 2ks.
// ---------------------------------------------------------------------------
template <int MODE>
__global__ __launch_bounds__(512, 2) void gemm_r4_kernel(
    const u16* __restrict__ Ain, const u16* __restrict__ BT,
    void* __restrict__ Cout, const float* __restrict__ bias,
    int N, int Kst, int Klen)
{
    constexpr int BUFU = 16384;                    // u16 per ring buffer (32KB)
    __shared__ __align__(16) u16 sm[4 * BUFU];     // 128 KB
    const int tid = threadIdx.x, lane = tid & 63, wid = tid >> 6;
    const int bid = blockIdx.x;
    const int xcd = bid & 7, loc = bid >> 3;       // bijective (256 % 8 == 0)
    const int mt = xcd * 4 + (loc & 3);
    const int rest = loc >> 2;                     // [0,8)
    int nt, ks;
    if constexpr (MODE == 0) { nt = rest;     ks = 0; }
    else                     { nt = rest & 3; ks = rest >> 2; }
    const int m0 = mt * 256, n0 = nt * 256;
    const int wm = wid & 1, wn = wid >> 1;         // 2 x 4 waves
    const int fr = lane & 15, fq = lane >> 4;

    const u16* Aeff = Ain + (size_t)ks * Klen;     // split-K slice base
    const u16* Beff = BT  + (size_t)ks * Klen;

    // glds global source (inverse-swizzled within-region byte offset)
    auto mk = [&](const u16* G, int r0, int q) -> const u16* {
        const int l = q ^ (((q >> 7) & 7) << 4);
        return G + (size_t)(r0 + (l >> 6)) * Kst + ((l & 63) >> 1);
    };
    const u16* pA0 = mk(Aeff, m0, tid * 16);       // A bytes [0,16384)
    const u16* pA1 = mk(Aeff, m0, tid * 16 + 8192);
    const u16* pB0 = mk(Beff, n0, tid * 16);       // B bytes [0,16384)
    const u16* pB1 = mk(Beff, n0, tid * 16 + 8192);

    auto stageA = [&](int t) {                     // A(t) -> buf (t&3)
        u16* bb = sm + (t & 3) * BUFU + (wid << 9);
        glds16(pA0 + t * 32, bb);
        glds16(pA1 + t * 32, bb + 4096);
    };
    auto stageB = [&](int t) {                     // B(t) -> buf (t&3)
        u16* bb = sm + (t & 3) * BUFU + 8192 + (wid << 9);
        glds16(pB0 + t * 32, bb);
        glds16(pB1 + t * 32, bb + 4096);
    };

    // fragment LDS offsets (same swizzle), u16 units, constant per thread
    int aoff[2][4], boff[4];
    #pragma unroll
    for (int rh = 0; rh < 2; ++rh)
        #pragma unroll
        for (int mi = 0; mi < 4; ++mi) {
            const int la = (wm * 128 + rh * 64 + mi * 16 + fr) * 64 + fq * 16;
            aoff[rh][mi] = (la ^ (((la >> 7) & 7) << 4)) >> 1;
        }
    #pragma unroll
    for (int ni = 0; ni < 4; ++ni) {
        const int lb = (wn * 64 + ni * 16 + fr) * 64 + fq * 16;
        boff[ni] = ((lb ^ (((lb >> 7) & 7) << 4)) >> 1) + 8192;
    }

    f32x4 acc[8][4] = {};
    bf16x8 af[4], bfr[4];
    const int NT = Klen >> 5;                      // 32-k tiles

    // prologue: stage tiles 0 and 1; wait tile 0 (8 outstanding -> 4)
    stageA(0); stageB(0); stageA(1); stageB(1);
    asm volatile("" ::: "memory");
    __builtin_amdgcn_s_waitcnt(WAIT_VM4);
    __builtin_amdgcn_sched_barrier(0);
    __builtin_amdgcn_s_barrier();

#define R4_TILE(t, STAGE, WVM, LAST)                                         \
  {                                                                          \
    const u16* cb_ = sm + ((t) & 3) * BUFU;                                  \
    /* ---- phase 0: rh=0, reads incl. B frags, stage A(t+2) ---- */         \
    _Pragma("unroll")                                                        \
    for (int i = 0; i < 4; ++i) af[i]  = *(const bf16x8*)(cb_ + aoff[0][i]); \
    _Pragma("unroll")                                                        \
    for (int i = 0; i < 4; ++i) bfr[i] = *(const bf16x8*)(cb_ + boff[i]);    \
    if (STAGE) stageA((t) + 2);                                              \
    asm volatile("" ::: "memory");                                           \
    __builtin_amdgcn_sched_barrier(0);                                       \
    __builtin_amdgcn_s_barrier();                                            \
    __builtin_amdgcn_s_waitcnt(WAIT_LGKM0);                                  \
    __builtin_amdgcn_sched_barrier(0);                                       \
    __builtin_amdgcn_s_setprio(1);                                           \
    _Pragma("unroll")                                                        \
    for (int mi = 0; mi < 4; ++mi)                                           \
      _Pragma("unroll")                                                      \
      for (int ni = 0; ni < 4; ++ni)                                         \
        acc[mi][ni] = __builtin_amdgcn_mfma_f32_16x16x32_bf16(               \
            bfr[ni], af[mi], acc[mi][ni], 0, 0, 0);                          \
    __builtin_amdgcn_s_setprio(0);                                           \
    asm volatile("" ::: "memory");                                           \
    __builtin_amdgcn_s_barrier();                                            \
    /* ---- phase 1: rh=1, A reads only (B reused), stage B(t+2) ---- */     \
    _Pragma("unroll")                                                        \
    for (int i = 0; i < 4; ++i) af[i] = *(const bf16x8*)(cb_ + aoff[1][i]);  \
    if (STAGE) stageB((t) + 2);                                              \
    asm volatile("" ::: "memory");                                           \
    if ((WVM) >= 0) __builtin_amdgcn_s_waitcnt((WVM) ? WAIT_VM4 : WAIT_VM0); \
    __builtin_amdgcn_sched_barrier(0);                                       \
    __builtin_amdgcn_s_barrier();                                            \
    __builtin_amdgcn_s_waitcnt(WAIT_LGKM0);                                  \
    __builtin_amdgcn_sched_barrier(0);                                       \
    __builtin_amdgcn_s_setprio(1);                                           \
    _Pragma("unroll")                                                        \
    for (int mi = 0; mi < 4; ++mi)                                           \
      _Pragma("unroll")                                                      \
      for (int ni = 0; ni < 4; ++ni)                                         \
        acc[4 + mi][ni] = __builtin_amdgcn_mfma_f32_16x16x32_bf16(           \
            bfr[ni], af[mi], acc[4 + mi][ni], 0, 0, 0);                      \
    __builtin_amdgcn_s_setprio(0);                                           \
    if (!(LAST)) {                                                           \
      asm volatile("" ::: "memory");                                         \
      __builtin_amdgcn_s_barrier();                                          \
    }                                                                        \
  }

    #pragma unroll 1
    for (int t = 0; t < NT - 2; ++t)
        R4_TILE(t, true, 1, false)          // stage t+2, vmcnt(4)
    R4_TILE(NT - 2, false, 0, false)        // no stage, vmcnt(0) drains last
    R4_TILE(NT - 1, false, -1, true)        // no stage, no vm wait
#undef R4_TILE

    // epilogue: acc[j] row = m0 + wm*128 + j*16 + fr (j=rh*4+mi: j*16 == rh*64+mi*16)
    #pragma unroll
    for (int ni = 0; ni < 4; ++ni) {
        const int colb = n0 + wn * 64 + ni * 16 + fq * 4;
        #pragma unroll
        for (int mi = 0; mi < 8; ++mi) {
            const int row = m0 + wm * 128 + mi * 16 + fr;
            f32x4 v = acc[mi][ni];
            if constexpr (MODE == 0) {
                const f32x4 bv = *(const f32x4*)(bias + colb);
                v.x += bv.x; v.y += bv.y; v.z += bv.z; v.w += bv.w;
                u16x4 o;
                o.x = f2bf(v.x); o.y = f2bf(v.y); o.z = f2bf(v.z); o.w = f2bf(v.w);
                *(u16x4*)((u16*)Cout + (size_t)row * N + colb) = o;
            } else {
                float* po = (float*)Cout + (size_t)row * N + colb;
                __hip_atomic_fetch_add(po + 0, v.x, __ATOMIC_RELAXED, __HIP_MEMORY_SCOPE_AGENT);
                __hip_atomic_fetch_add(po + 1, v.y, __ATOMIC_RELAXED, __HIP_MEMORY_SCOPE_AGENT);
                __hip_atomic_fetch_add(po + 2, v.z, __ATOMIC_RELAXED, __HIP_MEMORY_SCOPE_AGENT);
                __hip_atomic_fetch_add(po + 3, v.w, __ATOMIC_RELAXED, __HIP_MEMORY_SCOPE_AGENT);
            }
        }
    }
}

// ---------------------------------------------------------------------------
// Fused depthwise-conv(4) + 64-tap FIR (MFMA Toeplitz) + silu.
// Block: 64 t x 128 c, one batch. Conv fills VT[c][s] (bf16, s-window
// [t0-64, t0+64), row stride VROW=136). Conv loads vectorized u16x2
// (2 channels/thread, 256 B/wave-instr). FIR operands swapped -> each
// thread's f32x4 = 4 consecutive channels -> vectorized u16x4 Y stores.
// grid (16 c-tiles, 64 t-tiles, 2 batch) = 2048 blocks, 256 thr.
// ---------------------------------------------------------------------------
__global__ __launch_bounds__(256) void conv_fir_mfma_kernel(
    const u16* __restrict__ u, const float* __restrict__ cw,
    const float* __restrict__ cb, const u16* __restrict__ Amat64,
    u16* __restrict__ Y)
{
    __shared__ u16 VT[128 * VROW];          // 34816 B
    const int tid = threadIdx.x;
    const int c0 = blockIdx.x * 128, t0 = blockIdx.y * 64, b = blockIdx.z;
    // ---- conv phase: thread = 2 channel columns, 32 consecutive s ----
    {
        const int tx = tid & 63, ty = tid >> 6;
        const int cg = c0 + tx * 2;
        const f32x4 wA = *(const f32x4*)(cw + cg * 4);       // ch cg
        const f32x4 wB = *(const f32x4*)(cw + cg * 4 + 4);   // ch cg+1
        const float cb0 = cb[cg], cb1 = cb[cg + 1];
        const u16* ucol = u + (size_t)b * SEQ * D_INNER + cg;
        const int s0 = t0 - 64 + ty * 32;
        u16* vr0 = VT + (tx * 2)     * VROW + ty * 32;
        u16* vr1 = VT + (tx * 2 + 1) * VROW + ty * 32;
        if (t0 == 0 && ty < 2) {                 // s in [-64,-1): all zero
            const u16x4 z = {0, 0, 0, 0};
            #pragma unroll
            for (int j = 0; j < 8; j++) {
                *(u16x4*)(vr0 + j * 4) = z;
                *(u16x4*)(vr1 + j * 4) = z;
            }
        } else {                                  // here s0 >= 0 always
            float am3 = 0.f, am2 = 0.f, am1 = 0.f;
            float bm3 = 0.f, bm2 = 0.f, bm1 = 0.f;
            if (s0 > 0) {
                u16x2 d3 = *(const u16x2*)(ucol + (size_t)(s0 - 3) * D_INNER);
                u16x2 d2 = *(const u16x2*)(ucol + (size_t)(s0 - 2) * D_INNER);
                u16x2 d1 = *(const u16x2*)(ucol + (size_t)(s0 - 1) * D_INNER);
                am3 = bf2f(d3.x); bm3 = bf2f(d3.y);
                am2 = bf2f(d2.x); bm2 = bf2f(d2.y);
                am1 = bf2f(d1.x); bm1 = bf2f(d1.y);
            }
            #pragma unroll 2
            for (int j = 0; j < 8; j++) {
                const u16* p = ucol + (size_t)(s0 + j * 4) * D_INNER;
                u16x2 r0 = *(const u16x2*)(p);
                u16x2 r1 = *(const u16x2*)(p + (size_t)D_INNER);
                u16x2 r2 = *(const u16x2*)(p + (size_t)2 * D_INNER);
                u16x2 r3 = *(const u16x2*)(p + (size_t)3 * D_INNER);
                float a0 = bf2f(r0.x), b0 = bf2f(r0.y);
                float a1 = bf2f(r1.x), b1 = bf2f(r1.y);
                float a2 = bf2f(r2.x), b2 = bf2f(r2.y);
                float a3 = bf2f(r3.x), b3 = bf2f(r3.y);
                u16x4 oa, ob;
                oa.x = f2bf(cb0 + wA.x * am3 + wA.y * am2 + wA.z * am1 + wA.w * a0);
                oa.y = f2bf(cb0 + wA.x * am2 + wA.y * am1 + wA.z * a0  + wA.w * a1);
                oa.z = f2bf(cb0 + wA.x * am1 + wA.y * a0  + wA.z * a1  + wA.w * a2);
                oa.w = f2bf(cb0 + wA.x * a0  + wA.y * a1  + wA.z * a2  + wA.w * a3);
                ob.x = f2bf(cb1 + wB.x * bm3 + wB.y * bm2 + wB.z * bm1 + wB.w * b0);
                ob.y = f2bf(cb1 + wB.x * bm2 + wB.y * bm1 + wB.z * b0  + wB.w * b1);
                ob.z = f2bf(cb1 + wB.x * bm1 + wB.y * b0  + wB.z * b1  + wB.w * b2);
                ob.w = f2bf(cb1 + wB.x * b0  + wB.y * b1  + wB.z * b2  + wB.w * b3);
                *(u16x4*)(vr0 + j * 4) = oa;
                *(u16x4*)(vr1 + j * 4) = ob;
                am3 = a1; am2 = a2; am1 = a3;
                bm3 = b1; bm2 = b2; bm1 = b3;
            }
        }
    }
    __syncthreads();
    // ---- FIR phase: 4 waves, each 32t x 64c quadrant ----
    const int lane = tid & 63, wid = tid >> 6;
    const int wm = (wid & 1) * 32, wn = (wid >> 1) * 64;
    const int fr = lane & 15, fq = lane >> 4;
    f32x4 acc[2][4] = {};
    #pragma unroll
    for (int kq = 0; kq < 4; kq++) {
        const int k0 = kq * 32;
        bf16x8 af[2], bfr[4];
        #pragma unroll
        for (int mi = 0; mi < 2; mi++)
            af[mi] = *(const bf16x8*)(Amat64 + (wm + mi * 16 + fr) * 128 + k0 + fq * 8);
        #pragma unroll
        for (int ni = 0; ni < 4; ni++)
            bfr[ni] = *(const bf16x8*)(VT + (wn + ni * 16 + fr) * VROW + k0 + fq * 8);
        #pragma unroll
        for (int mi = 0; mi < 2; mi++)
            #pragma unroll
            for (int ni = 0; ni < 4; ni++)
                acc[mi][ni] = __builtin_amdgcn_mfma_f32_16x16x32_bf16(
                    bfr[ni], af[mi], acc[mi][ni], 0, 0, 0);
    }
    // epilogue: thread owns t = ..+fr, channels c = ..+fq*4+{0..3}
    #pragma unroll
    for (int ni = 0; ni < 4; ni++) {
        const int cbase = c0 + wn + ni * 16 + fq * 4;
        #pragma unroll
        for (int mi = 0; mi < 2; mi++) {
            const int trow = t0 + wm + mi * 16 + fr;
            f32x4 v = acc[mi][ni];
            u16x4 o;
            o.x = f2bf(v.x / (1.f + __expf(-v.x)));
            o.y = f2bf(v.y / (1.f + __expf(-v.y)));
            o.z = f2bf(v.z / (1.f + __expf(-v.z)));
            o.w = f2bf(v.w / (1.f + __expf(-v.w)));
            *(u16x4*)(Y + ((size_t)(b * SEQ + trow)) * D_INNER + cbase) = o;
        }
    }
}

// ---------------------------------------------------------------------------
extern "C" void kernel_launch(void* const* d_in, const int* in_sizes, int n_in,
                              void* d_out, int out_size, void* d_ws, size_t ws_size,
                              hipStream_t stream)
{
    const float* x    = (const float*)d_in[0];
    const float* Win  = (const float*)d_in[1];
    const float* bin  = (const float*)d_in[2];
    const float* cw   = (const float*)d_in[3];
    const float* cb   = (const float*)d_in[4];
    const float* A    = (const float*)d_in[5];
    const float* Bp   = (const float*)d_in[6];
    const float* Cp   = (const float*)d_in[7];
    const float* Dp   = (const float*)d_in[8];
    const float* Wout = (const float*)d_in[9];
    const float* bout = (const float*)d_in[10];
    float* out = (float*)d_out;

    char* ws = (char*)d_ws;
    u16* xb     = (u16*)(ws);                      // 8192x1024 bf16   16 MB
    u16* WinT   = (u16*)(ws + 16777216);           // 2048x1024 bf16    4 MB
    u16* WoutT  = (u16*)(ws + 20971520);           // 1024x2048 bf16    4 MB
    u16* u      = (u16*)(ws + 25165824);           // 8192x2048 bf16   32 MB
    u16* Y      = (u16*)(ws + 58720256);           // 8192x2048 bf16   32 MB
    u16* Amat64 = (u16*)(ws + 92274688);           // 64x128 bf16      16 KB

    // conversions/transposes/Amat + bias-prefill of out (for GEMM2 atomics)
    prep_kernel<<<20481, 256, 0, stream>>>(x, xb, Win, WinT, Wout, WoutT,
                                           A, Bp, Cp, Dp, Amat64, bout, out);
    // u = x @ W_in + b_in  (bf16 out): M=8192,N=2048,K=1024, 256x256 tiles
    gemm_r4_kernel<0><<<256, 512, 0, stream>>>(xb, WinT, u, bin,
                                               D_INNER, D_MODEL, D_MODEL);
    // fused conv + SSM-as-FIR (MFMA Toeplitz) + silu -> Y
    conv_fir_mfma_kernel<<<dim3(16, 64, 2), 256, 0, stream>>>(u, cw, cb, Amat64, Y);
    // out += Y @ W_out (fp32 atomics, split-K=2): M=8192,N=1024,K=2048
    gemm_r4_kernel<2><<<256, 512, 0, stream>>>(Y, WoutT, out, nullptr,
                                               D_MODEL, D_INNER, D_MODEL);
}

// Round 4
// 220.540 us; speedup vs baseline: 1.9042x; 1.9042x over previous
//
#include <hip/hip_runtime.h>

typedef unsigned short u16;
typedef float  f32x4  __attribute__((ext_vector_type(4)));
typedef __bf16 bf16x8 __attribute__((ext_vector_type(8)));
typedef u16    u16x2  __attribute__((ext_vector_type(2)));
typedef u16    u16x4  __attribute__((ext_vector_type(4)));

#define D_MODEL 1024
#define D_INNER 2048
#define B_SZ    2
#define SEQ     4096
#define MROWS   (B_SZ * SEQ)       // 8192
#define LTAPS   32                 // f[tau] ~ 0.4^tau -> < 1e-12 at 32
#define AW      96                 // FIR window per 64-t tile (64 + LTAPS)
#define VROW    104                // VT row stride (u16): 208 B, 16B-aligned

__device__ __forceinline__ u16 f2bf(float f) {
    return __builtin_bit_cast(u16, (__bf16)f);   // HW v_cvt (RTNE) on gfx950
}
__device__ __forceinline__ float bf2f(u16 h) {
    unsigned u = ((unsigned)h) << 16;
    return __builtin_bit_cast(float, u);
}

typedef __attribute__((address_space(1))) void gv_t;
typedef __attribute__((address_space(3))) void lv_t;
__device__ __forceinline__ void glds16(const u16* g, u16* l) {
    __builtin_amdgcn_global_load_lds((gv_t*)g, (lv_t*)l, 16, 0, 0);
}
// gfx9 waitcnt imm: vm[3:0]+[15:14], exp[6:4], lgkm[13:8]
#define WAIT_VM(n) (0x0F70 | (n))  // vmcnt(n) (n<16)
#define WAIT_LGKM0 0xC07F          // lgkmcnt(0), vm/exp max

// ---------------------------------------------------------------------------
// Prep (one launch): blocks [0,8192) cvt x->bf16; [8192,10240) transpose Win;
// [10240,12288) transpose Wout; block 12288 builds Amat32[64][96] bf16:
// Amat32[i][j] = f[32+i-j], f[tau] = Cp^T tanh(A)^tau Bp (+Dp at tau=0).
// ---------------------------------------------------------------------------
__device__ __forceinline__ void transpose_tile(
    const float* __restrict__ in, u16* __restrict__ out,
    int R, int C, int c0, int r0, int tid, float (*tile)[33])
{
    const int tx = tid & 31, ty = tid >> 5;   // 32 x 8
    for (int k = 0; k < 32; k += 8)
        tile[ty + k][tx] = in[(size_t)(r0 + ty + k) * C + c0 + tx];
    __syncthreads();
    for (int k = 0; k < 32; k += 8)
        out[(size_t)(c0 + ty + k) * R + r0 + tx] = f2bf(tile[tx][ty + k]);
}

__global__ __launch_bounds__(256) void prep_kernel(
    const float* __restrict__ x, u16* __restrict__ xb,
    const float* __restrict__ Win, u16* __restrict__ WinT,
    const float* __restrict__ Wout, u16* __restrict__ WoutT,
    const float* __restrict__ A, const float* __restrict__ Bp,
    const float* __restrict__ Cp, const float* __restrict__ Dp,
    u16* __restrict__ Amat32)
{
    __shared__ float tile[32][33];
    __shared__ float fs[LTAPS];
    const int bx = blockIdx.x, tid = threadIdx.x;
    if (bx < 8192) {
        size_t i = ((size_t)bx * 256 + tid) * 4;
        f32x4 v = *(const f32x4*)(x + i);
        u16x4 o;
        o.x = f2bf(v.x); o.y = f2bf(v.y); o.z = f2bf(v.z); o.w = f2bf(v.w);
        *(u16x4*)(xb + i) = o;
    } else if (bx < 10240) {
        const int flat = bx - 8192;                      // Win: 1024 x 2048
        transpose_tile(Win, WinT, 1024, 2048,
                       (flat & 63) * 32, (flat >> 6) * 32, tid, tile);
    } else if (bx < 12288) {
        const int flat = bx - 10240;                     // Wout: 2048 x 1024
        transpose_tile(Wout, WoutT, 2048, 1024,
                       (flat & 31) * 32, (flat >> 5) * 32, tid, tile);
    } else {
        if (tid < 64) {
            const int i = tid & 15;          // lanes replicate in groups of 16
            float Atr[16];
            for (int j = 0; j < 16; j++) Atr[j] = tanhf(A[i * 16 + j]);
            float p = Bp[i];
            const float c  = Cp[i];
            const float d0 = Dp[0];
            for (int t = 0; t < LTAPS; t++) {
                float fv = c * p;
                fv += __shfl_xor(fv, 1); fv += __shfl_xor(fv, 2);
                fv += __shfl_xor(fv, 4); fv += __shfl_xor(fv, 8);
                if (tid == 0) fs[t] = fv + (t == 0 ? d0 : 0.f);
                float n0 = 0.f, n1 = 0.f, n2 = 0.f, n3 = 0.f;
                #pragma unroll
                for (int j = 0; j < 4; j++) {
                    n0 = fmaf(Atr[j],      __shfl(p, j),      n0);
                    n1 = fmaf(Atr[j + 4],  __shfl(p, j + 4),  n1);
                    n2 = fmaf(Atr[j + 8],  __shfl(p, j + 8),  n2);
                    n3 = fmaf(Atr[j + 12], __shfl(p, j + 12), n3);
                }
                p = (n0 + n1) + (n2 + n3);
            }
        }
        __syncthreads();
        for (int idx = tid; idx < 64 * AW; idx += 256) {
            const int i = idx / AW, j = idx - i * AW;
            const int tau = LTAPS + i - j;
            float v = (tau >= 0 && tau < LTAPS) ? fs[tau] : 0.f;
            Amat32[idx] = f2bf(v);
        }
    }
}

// ---------------------------------------------------------------------------
// Ring-4 bt-GEMM, ONE phase per 32-k sub-tile (32 MFMA/barrier for GEMM1).
// C[m][n] = sum_k A[m][k]*BT[n][k] + bias[n].
// 512 thr = 8 waves (WM x WN), wave tile (BM/WM) x (BN/WN).
// Evidence r0-r3: time ~= #phases x ~1630cy regardless of phase content
// (64 phases -> 43.6us in three different schedules). So: HALVE phase count
// by merging each 32-k sub-tile into a single phase with FM+FN ds_reads and
// FM*FN MFMAs (GEMM1: 12 reads, 32 MFMA -- AITER's ~32 MFMA/barrier).
// LDS: 4 ring sub-buffers of (BM+BN)*32 u16. Phase p reads sub p, stages
// sub p+2 (slot (p+2)&3 dead since p-2). vmcnt(L) per phase (L = glds/phase),
// counted, drains to 0 only at phase NT-2.
// Swizzle (verified 0 conflicts): within-region byte q ^= ((q>>7)&7)<<4 on
// the GLOBAL source addr (LDS dest linear for global_load_lds) and on
// ds_read addrs. XCD chunking: 4 consecutive mt per XCD.
// GEMM1 <256,256,2,4,0>: 32 phases. GEMM2 <256,128,4,2,1>: 64 light phases.
// ---------------------------------------------------------------------------
template <int BM, int BN, int WM, int WN, int MODE>
__global__ __launch_bounds__(512, 2) void gemm_k1_kernel(
    const u16* __restrict__ Ain, const u16* __restrict__ BT,
    void* __restrict__ Cout, const float* __restrict__ bias,
    int N, int K)
{
    constexpr int FM = BM / WM / 16, FN = BN / WN / 16;
    constexpr int SBU = (BM + BN) * 32;            // u16 per sub-buffer
    constexpr int AGL = BM / 128, BGL = BN / 128;  // glds per phase (A, B)
    constexpr int LGL = AGL + BGL;
    static_assert(WM * WN == 8, "8 waves");
    __shared__ __align__(16) u16 sm[4 * SBU];
    const int tid = threadIdx.x, lane = tid & 63, wid = tid >> 6;
    const int bid = blockIdx.x;
    const int xcd = bid & 7, loc = bid >> 3;       // bijective (256 % 8 == 0)
    const int mt = xcd * 4 + (loc & 3), nt = loc >> 2;
    const int m0 = mt * BM, n0 = nt * BN;
    const int wm = wid % WM, wn = wid / WM;
    const int fr = lane & 15, fq = lane >> 4;

    // glds global source (inverse-swizzled within-region byte offset q)
    auto mk = [&](const u16* G, int r0, int q) -> const u16* {
        const int l = q ^ (((q >> 7) & 7) << 4);
        return G + (size_t)(r0 + (l >> 6)) * K + ((l & 63) >> 1);
    };
    const u16* pA[AGL];
    const u16* pB[BGL];
    #pragma unroll
    for (int j = 0; j < AGL; ++j) pA[j] = mk(Ain, m0, tid * 16 + j * 8192);
    #pragma unroll
    for (int j = 0; j < BGL; ++j) pB[j] = mk(BT, n0, tid * 16 + j * 8192);

    auto stage = [&](int t) {                      // sub-tile t -> slot t&3
        u16* sb = sm + (t & 3) * SBU;
        #pragma unroll
        for (int j = 0; j < AGL; ++j)
            glds16(pA[j] + t * 32, sb + tid * 8 + j * 4096);
        #pragma unroll
        for (int j = 0; j < BGL; ++j)
            glds16(pB[j] + t * 32, sb + BM * 32 + tid * 8 + j * 4096);
    };

    // fragment LDS offsets (same swizzle), u16 units, constant per thread
    int aoff[FM], boff[FN];
    #pragma unroll
    for (int mi = 0; mi < FM; ++mi) {
        const int la = (wm * (BM / WM) + mi * 16 + fr) * 64 + fq * 16;
        aoff[mi] = (la ^ (((la >> 7) & 7) << 4)) >> 1;
    }
    #pragma unroll
    for (int ni = 0; ni < FN; ++ni) {
        const int lb = (wn * (BN / WN) + ni * 16 + fr) * 64 + fq * 16;
        boff[ni] = ((lb ^ (((lb >> 7) & 7) << 4)) >> 1) + BM * 32;
    }

    f32x4 acc[FM][FN] = {};
    const int NT = K >> 5;                         // 32-k sub-tiles

    // prologue: stage subs 0,1 (2L outstanding); wait sub 0 -> vmcnt(L)
    stage(0); stage(1);
    asm volatile("" ::: "memory");
    __builtin_amdgcn_s_waitcnt(WAIT_VM(LGL));
    __builtin_amdgcn_sched_barrier(0);
    __builtin_amdgcn_s_barrier();

#define K1_PHASE(p, DOSTAGE, WVM)                                            \
  {                                                                          \
    const u16* sb_ = sm + ((p) & 3) * SBU;                                   \
    bf16x8 af[FM], bfr[FN];                                                  \
    _Pragma("unroll")                                                        \
    for (int mi = 0; mi < FM; ++mi)                                          \
      af[mi] = *(const bf16x8*)(sb_ + aoff[mi]);                             \
    _Pragma("unroll")                                                        \
    for (int ni = 0; ni < FN; ++ni)                                          \
      bfr[ni] = *(const bf16x8*)(sb_ + boff[ni]);                            \
    if (DOSTAGE) stage((p) + 2);                                             \
    asm volatile("" ::: "memory");                                           \
    __builtin_amdgcn_sched_barrier(0);                                       \
    __builtin_amdgcn_s_barrier();                                            \
    __builtin_amdgcn_s_waitcnt(WAIT_LGKM0);                                  \
    __builtin_amdgcn_sched_barrier(0);                                       \
    __builtin_amdgcn_s_setprio(1);                                           \
    _Pragma("unroll")                                                        \
    for (int mi = 0; mi < FM; ++mi)                                          \
      _Pragma("unroll")                                                      \
      for (int ni = 0; ni < FN; ++ni)                                        \
        acc[mi][ni] = __builtin_amdgcn_mfma_f32_16x16x32_bf16(               \
            bfr[ni], af[mi], acc[mi][ni], 0, 0, 0);                          \
    __builtin_amdgcn_s_setprio(0);                                           \
    if ((WVM) >= 0) {                                                        \
      asm volatile("" ::: "memory");                                         \
      __builtin_amdgcn_s_waitcnt(WAIT_VM(WVM));                              \
      __builtin_amdgcn_sched_barrier(0);                                     \
      __builtin_amdgcn_s_barrier();                                          \
    }                                                                        \
  }

    #pragma unroll 1
    for (int p = 0; p < NT - 2; ++p)
        K1_PHASE(p, true, LGL)          // stage p+2; counted vmcnt(L)
    K1_PHASE(NT - 2, false, 0)          // drain for last sub-tile
    K1_PHASE(NT - 1, false, -1)         // final: no wait/barrier
#undef K1_PHASE

    // epilogue: thread owns row m = ..+mi*16+fr, cols n = ..+ni*16+fq*4+{0..3}
    #pragma unroll
    for (int ni = 0; ni < FN; ++ni) {
        const int colb = n0 + wn * (BN / WN) + ni * 16 + fq * 4;
        const f32x4 bv = *(const f32x4*)(bias + colb);
        #pragma unroll
        for (int mi = 0; mi < FM; ++mi) {
            const int row = m0 + wm * (BM / WM) + mi * 16 + fr;
            f32x4 v = acc[mi][ni];
            v.x += bv.x; v.y += bv.y; v.z += bv.z; v.w += bv.w;
            if constexpr (MODE == 0) {
                u16x4 o;
                o.x = f2bf(v.x); o.y = f2bf(v.y); o.z = f2bf(v.z); o.w = f2bf(v.w);
                *(u16x4*)((u16*)Cout + (size_t)row * N + colb) = o;
            } else {
                *(f32x4*)((float*)Cout + (size_t)row * N + colb) = v;
            }
        }
    }
}

// ---------------------------------------------------------------------------
// Fused depthwise-conv(4) + 32-tap FIR (MFMA Toeplitz) + silu.
// Block: 64 t x 128 c, one batch. Conv fills VT[c][j] (bf16, s-window
// [t0-32, t0+64), 96 cols, row stride VROW=104). FIR: Amat32[64][96],
// K=96 (3 MFMA k-steps). grid (16, 64, 2) = 2048 blocks, 256 thr.
// ---------------------------------------------------------------------------
__global__ __launch_bounds__(256) void conv_fir_mfma_kernel(
    const u16* __restrict__ u, const float* __restrict__ cw,
    const float* __restrict__ cb, const u16* __restrict__ Amat32,
    u16* __restrict__ Y)
{
    __shared__ u16 VT[128 * VROW];          // 26624 B
    const int tid = threadIdx.x;
    const int c0 = blockIdx.x * 128, t0 = blockIdx.y * 64, b = blockIdx.z;
    // ---- conv phase: thread = 2 channel columns ----
    {
        const int tx = tid & 63, ty = tid >> 6;   // 64 ch-pairs x 4 s-groups
        const int cg = c0 + tx * 2;
        const f32x4 wA = *(const f32x4*)(cw + cg * 4);       // ch cg
        const f32x4 wB = *(const f32x4*)(cw + cg * 4 + 4);   // ch cg+1
        const float cb0 = cb[cg], cb1 = cb[cg + 1];
        const u16* ucol = u + (size_t)b * SEQ * D_INNER + cg;
        u16* vr0 = VT + (tx * 2)     * VROW;
        u16* vr1 = VT + (tx * 2 + 1) * VROW;

        // computes NJ*4 outputs starting at s0 (writes idx0..), prevs guarded
        auto conv_run = [&](int s0, int idx0, int NJ) {
            float am3 = 0.f, am2 = 0.f, am1 = 0.f;
            float bm3 = 0.f, bm2 = 0.f, bm1 = 0.f;
            if (s0 > 0) {
                u16x2 d3 = *(const u16x2*)(ucol + (size_t)(s0 - 3) * D_INNER);
                u16x2 d2 = *(const u16x2*)(ucol + (size_t)(s0 - 2) * D_INNER);
                u16x2 d1 = *(const u16x2*)(ucol + (size_t)(s0 - 1) * D_INNER);
                am3 = bf2f(d3.x); bm3 = bf2f(d3.y);
                am2 = bf2f(d2.x); bm2 = bf2f(d2.y);
                am1 = bf2f(d1.x); bm1 = bf2f(d1.y);
            }
            #pragma unroll 2
            for (int j = 0; j < NJ; j++) {
                const u16* p = ucol + (size_t)(s0 + j * 4) * D_INNER;
                u16x2 r0 = *(const u16x2*)(p);
                u16x2 r1 = *(const u16x2*)(p + (size_t)D_INNER);
                u16x2 r2 = *(const u16x2*)(p + (size_t)2 * D_INNER);
                u16x2 r3 = *(const u16x2*)(p + (size_t)3 * D_INNER);
                float a0 = bf2f(r0.x), b0 = bf2f(r0.y);
                float a1 = bf2f(r1.x), b1 = bf2f(r1.y);
                float a2 = bf2f(r2.x), b2 = bf2f(r2.y);
                float a3 = bf2f(r3.x), b3 = bf2f(r3.y);
                u16x4 oa, ob;
                oa.x = f2bf(cb0 + wA.x * am3 + wA.y * am2 + wA.z * am1 + wA.w * a0);
                oa.y = f2bf(cb0 + wA.x * am2 + wA.y * am1 + wA.z * a0  + wA.w * a1);
                oa.z = f2bf(cb0 + wA.x * am1 + wA.y * a0  + wA.z * a1  + wA.w * a2);
                oa.w = f2bf(cb0 + wA.x * a0  + wA.y * a1  + wA.z * a2  + wA.w * a3);
                ob.x = f2bf(cb1 + wB.x * bm3 + wB.y * bm2 + wB.z * bm1 + wB.w * b0);
                ob.y = f2bf(cb1 + wB.x * bm2 + wB.y * bm1 + wB.z * b0  + wB.w * b1);
                ob.z = f2bf(cb1 + wB.x * bm1 + wB.y * b0  + wB.z * b1  + wB.w * b2);
                ob.w = f2bf(cb1 + wB.x * b0  + wB.y * b1  + wB.z * b2  + wB.w * b3);
                *(u16x4*)(vr0 + idx0 + j * 4) = oa;
                *(u16x4*)(vr1 + idx0 + j * 4) = ob;
                am3 = a1; am2 = a2; am1 = a3;
                bm3 = b1; bm2 = b2; bm1 = b3;
            }
        };

        if (t0 == 0) {
            // zero cols [0,32) (s<0): thread zeroes row tid>>1, 16 cols
            u16* zr = VT + (tid >> 1) * VROW + (tid & 1) * 16;
            const u16x4 z = {0, 0, 0, 0};
            #pragma unroll
            for (int j = 0; j < 4; j++) *(u16x4*)(zr + j * 4) = z;
            // compute s in [0,64): 4 ty-groups x 16 s
            conv_run(ty * 16, 32 + ty * 16, 4);
        } else {
            // s0 = t0-32+ty*24 >= 32 > 0 always (t0 >= 64)
            conv_run(t0 - 32 + ty * 24, ty * 24, 6);
        }
    }
    __syncthreads();
    // ---- FIR phase: 4 waves, each 32t x 64c quadrant ----
    const int lane = tid & 63, wid = tid >> 6;
    const int wm = (wid & 1) * 32, wn = (wid >> 1) * 64;
    const int fr = lane & 15, fq = lane >> 4;
    f32x4 acc[2][4] = {};
    #pragma unroll
    for (int kq = 0; kq < 3; kq++) {
        const int k0 = kq * 32;
        bf16x8 af[2], bfr[4];
        #pragma unroll
        for (int mi = 0; mi < 2; mi++)
            af[mi] = *(const bf16x8*)(Amat32 + (wm + mi * 16 + fr) * AW + k0 + fq * 8);
        #pragma unroll
        for (int ni = 0; ni < 4; ni++)
            bfr[ni] = *(const bf16x8*)(VT + (wn + ni * 16 + fr) * VROW + k0 + fq * 8);
        #pragma unroll
        for (int mi = 0; mi < 2; mi++)
            #pragma unroll
            for (int ni = 0; ni < 4; ni++)
                acc[mi][ni] = __builtin_amdgcn_mfma_f32_16x16x32_bf16(
                    bfr[ni], af[mi], acc[mi][ni], 0, 0, 0);
    }
    // epilogue: thread owns t = ..+fr, channels c = ..+fq*4+{0..3}
    #pragma unroll
    for (int ni = 0; ni < 4; ni++) {
        const int cbase = c0 + wn + ni * 16 + fq * 4;
        #pragma unroll
        for (int mi = 0; mi < 2; mi++) {
            const int trow = t0 + wm + mi * 16 + fr;
            f32x4 v = acc[mi][ni];
            u16x4 o;
            o.x = f2bf(v.x / (1.f + __expf(-v.x)));
            o.y = f2bf(v.y / (1.f + __expf(-v.y)));
            o.z = f2bf(v.z / (1.f + __expf(-v.z)));
            o.w = f2bf(v.w / (1.f + __expf(-v.w)));
            *(u16x4*)(Y + ((size_t)(b * SEQ + trow)) * D_INNER + cbase) = o;
        }
    }
}

// ---------------------------------------------------------------------------
extern "C" void kernel_launch(void* const* d_in, const int* in_sizes, int n_in,
                              void* d_out, int out_size, void* d_ws, size_t ws_size,
                              hipStream_t stream)
{
    const float* x    = (const float*)d_in[0];
    const float* Win  = (const float*)d_in[1];
    const float* bin  = (const float*)d_in[2];
    const float* cw   = (const float*)d_in[3];
    const float* cb   = (const float*)d_in[4];
    const float* A    = (const float*)d_in[5];
    const float* Bp   = (const float*)d_in[6];
    const float* Cp   = (const float*)d_in[7];
    const float* Dp   = (const float*)d_in[8];
    const float* Wout = (const float*)d_in[9];
    const float* bout = (const float*)d_in[10];
    float* out = (float*)d_out;

    char* ws = (char*)d_ws;
    u16* xb     = (u16*)(ws);                      // 8192x1024 bf16   16 MB
    u16* WinT   = (u16*)(ws + 16777216);           // 2048x1024 bf16    4 MB
    u16* WoutT  = (u16*)(ws + 20971520);           // 1024x2048 bf16    4 MB
    u16* u      = (u16*)(ws + 25165824);           // 8192x2048 bf16   32 MB
    u16* Y      = (u16*)(ws + 58720256);           // 8192x2048 bf16   32 MB
    u16* Amat32 = (u16*)(ws + 92274688);           // 64x96 bf16       12 KB

    // all conversions/transposes/setup in one launch
    prep_kernel<<<12289, 256, 0, stream>>>(x, xb, Win, WinT, Wout, WoutT,
                                           A, Bp, Cp, Dp, Amat32);
    // u = x @ W_in + b_in  (bf16 out): M=8192,N=2048,K=1024 -> 32 phases
    gemm_k1_kernel<256, 256, 2, 4, 0><<<256, 512, 0, stream>>>(
        xb, WinT, u, bin, D_INNER, D_MODEL);
    // fused conv + SSM-as-FIR (MFMA Toeplitz) + silu -> Y
    conv_fir_mfma_kernel<<<dim3(16, 64, 2), 256, 0, stream>>>(u, cw, cb, Amat32, Y);
    // out = Y @ W_out + b_out  (fp32 out): M=8192,N=1024,K=2048 -> 64 phases
    gemm_k1_kernel<256, 128, 4, 2, 1><<<256, 512, 0, stream>>>(
        Y, WoutT, out, bout, D_MODEL, D_INNER);
}